// Round 6
// baseline (223.930 us; speedup 1.0000x reference)
//
#include <hip/hip_runtime.h>
#include <math.h>

// Problem constants (fixed by reference setup_inputs): pred [32,1,512,512] f32
#define IMG_W 512
#define IMG_H 512
#define HW (IMG_W * IMG_H)      // 262144 = 2^18
#define LOGHW 18
#define NIMG 32
#define NTOT (NIMG * HW)        // 8388608
#define TILE 64
#define TPI 64                  // 8x8 tiles of 64x64 per image
#define NTILE (NIMG * TPI)      // 2048
#define CPI 64                  // stat-chunks per image (4096 px each)
#define NSCHUNK (NIMG * CPI)    // 2048
#define VBORD ((8 - 1) * IMG_H)                 // 3584 vertical-border pairs/img
#define BORD_PER_IMG (VBORD + (8 - 1) * IMG_W)  // 7168
#define NBORD (NIMG * BORD_PER_IMG)             // 229376

#define AL_ACQ(p) __hip_atomic_load((p), __ATOMIC_ACQUIRE, __HIP_MEMORY_SCOPE_AGENT)
#define AS_RLX(p, v) __hip_atomic_store((p), (v), __ATOMIC_RELAXED, __HIP_MEMORY_SCOPE_AGENT)

// ---------------- lock-free min-index union-find ----------------------------
__device__ __forceinline__ void uf_unite(int* L, int a, int b) {
    while (true) {
        // find roots (reads may be stale -> only costs retries, never wrong)
        int p = ((volatile int*)L)[a];
        while (p != a) { a = p; p = ((volatile int*)L)[a]; }
        p = ((volatile int*)L)[b];
        while (p != b) { b = p; p = ((volatile int*)L)[b]; }
        if (a == b) return;
        if (a < b) { int t = a; a = b; b = t; }  // a > b
        int old = atomicMin(&L[a], b);
        if (old == a) return;
        a = old;
    }
}

// ---------------- K1: CCL (ballot row-runs + vertical unites) + base BCE ----
// One block (1024 thr, 16 waves) per 64x64 tile; tile row width == wave width.
// Row runs labeled in O(1) via ballot (run start = min index of run). Only
// vertical run-pair contacts go through the LDS union-find (~750/tile).
// Local raster order == global raster order within a tile, so min-index roots
// are exact. Base BCE term sum(fmax(log(1-p),-100)) fused here with native
// __logf (~4 VALU ops/px) since pred is already in registers — this removes
// the separate 33.5 MB pred pass that k_loss did in R5.
__global__ __launch_bounds__(1024) void k_local(const float* __restrict__ pred,
                                                int* __restrict__ L,
                                                float* __restrict__ partials,
                                                unsigned int* __restrict__ counters) {
    __shared__ int lab[TILE * TILE];   // 16 KB
    __shared__ float sred[1024];       // 4 KB
    int tile = blockIdx.x;
    int img = tile >> 6;
    int t = tile & (TPI - 1);
    int ty = t >> 3, tx = t & 7;
    int baseLocal = (ty * TILE) * IMG_W + tx * TILE;  // image-local origin
    const float* pi = pred + ((size_t)img << LOGHW);
    int* Li = L + ((size_t)img << LOGHW);
    int tid = threadIdx.x;
    int lane = tid & 63, wave = tid >> 6;             // wave 0..15

    float acc = 0.0f;
    // ---- pass 1: row-run labels via ballot (wave w handles rows r%16==w) ---
#pragma unroll
    for (int j = 0; j < 4; j++) {
        int row = wave + j * 16;
        float p = pi[baseLocal + row * IMG_W + lane];
        acc += fmaxf(__logf(1.0f - p), -100.0f);   // 1-p exact for p>=0.5
        bool fg = (p >= 0.5f);
        unsigned long long bal = __ballot(fg);
        unsigned long long starts = bal & ~(bal << 1);
        unsigned long long maskle =
            (lane == 63) ? ~0ULL : ((1ULL << (lane + 1)) - 1ULL);
        int lb = -1;
        if (fg) {
            unsigned long long pre = starts & maskle;   // nonzero when fg
            lb = row * TILE + (63 - __builtin_clzll(pre));
        }
        lab[row * TILE + lane] = lb;
    }
    __syncthreads();
    // ---- pass 2: vertical unites, one per contact-run ----------------------
#pragma unroll
    for (int j = 0; j < 4; j++) {
        int row = wave + j * 16;
        if (row == 0) continue;                   // wave-uniform
        int i = row * TILE + lane;
        bool c = (lab[i] >= 0) && (lab[i - TILE] >= 0);
        unsigned long long cb = __ballot(c);
        unsigned long long cs = cb & ~(cb << 1);  // first lane of each contact
        if ((cs >> lane) & 1ULL) uf_unite(lab, i, i - TILE);
    }
    __syncthreads();
    // ---- pass 3: flatten (path halving) + write image-local roots (int4) ---
    {
        int i4 = tid * 4;
        int ly = i4 >> 6, lx = i4 & 63;
        int4 o;
        int* op = (int*)&o;
#pragma unroll
        for (int k = 0; k < 4; k++) {
            int x = i4 + k;
            int p = lab[x];
            if (p < 0) op[k] = -1;
            else {
                while (p != x) {
                    int g = lab[p];     // grandparent (or parent if p is root)
                    lab[x] = g;         // path halving: benign race
                    x = g;
                    p = lab[x];
                }
                op[k] = baseLocal + (x >> 6) * IMG_W + (x & 63);
            }
        }
        *(int4*)(Li + baseLocal + ly * IMG_W + lx) = o;
    }
    // ---- base BCE block reduce ---------------------------------------------
    sred[tid] = acc;
    __syncthreads();
    for (int s = 512; s > 0; s >>= 1) {
        if (tid < s) sred[tid] += sred[tid + s];
        __syncthreads();
    }
    if (tid == 0) partials[blockIdx.x] = sred[0];
    // zero the handshake counters for the later kernels (re-poisoned to 0xAA)
    if (blockIdx.x == 0 && tid <= NIMG) counters[tid] = 0u;
}

// ---------------- K2: cross-tile border unites, ballot-compressed -----------
// Consecutive contact pairs along an edge are redundant (edge-parallel
// neighbors already united intra-tile): unite only at contact-run starts.
// Waves never straddle edges: 512, VBORD, BORD_PER_IMG all multiples of 64.
__global__ void k_border(int* __restrict__ L) {
    int gid = blockIdx.x * blockDim.x + threadIdx.x;
    int img = gid / BORD_PER_IMG;                // wave-uniform
    int r = gid - img * BORD_PER_IMG;
    int* Li = L + ((size_t)img << LOGHW);
    int a, b;
    if (r < VBORD) {                             // wave-uniform branch
        int k = r >> 9, y = r & 511;
        int x = k * TILE + (TILE - 1);
        a = y * IMG_W + x; b = a + 1;
    } else {
        int r2 = r - VBORD;
        int k = r2 >> 9, x = r2 & 511;
        int y = k * TILE + (TILE - 1);
        a = y * IMG_W + x; b = a + IMG_W;
    }
    bool c = (Li[a] >= 0) && (Li[b] >= 0);
    unsigned long long cb = __ballot(c);
    unsigned long long cs = cb & ~(cb << 1);     // contact-run starts
    if ((cs >> (threadIdx.x & 63)) & 1ULL) uf_unite(Li, a, b);
}

// ---------------- K3: per-chunk stats + fused per-image rv ------------------
// Each block: stats over its 4096-px chunk (root count / max root / min fg>=1;
// root flags L[i]==i are compression-invariant -> no chasing). Stats go out
// via relaxed agent atomics; an acq_rel counter elects the 64th finisher per
// image, which computes v and selects the v-th root -> rv[img].
// v = argmax(lf[1:]) + 1 equals: index of LAST root (if >=1); else (single
// component rooted at 0) first fg index >=1, or 1 if none; else 1.
// rv = v-th root in raster order if 1<=v<=num, else -2 (target empty).
__global__ __launch_bounds__(256) void k_stats_rv(const int* __restrict__ L,
                                                  int* __restrict__ cntArr,
                                                  int* __restrict__ maxArr,
                                                  int* __restrict__ minArr,
                                                  unsigned int* __restrict__ counters,
                                                  int* __restrict__ rv) {
    __shared__ int s1[256], s2[256], s3[256];
    __shared__ int sel_chunk, sel_base, result;
    __shared__ unsigned int oldc;
    int chunk = blockIdx.x;
    int img = chunk >> 6;
    int baseL = (chunk & 63) * 4096;             // image-local
    const int* Li = L + ((size_t)img << LOGHW);
    int t = threadIdx.x;
    int cnt = 0, mx = -1, mn = HW;
#pragma unroll
    for (int j = 0; j < 4; j++) {
        int off = baseL + (t + j * 256) * 4;
        int4 l4 = *(const int4*)(Li + off);
        const int* lp = (const int*)&l4;
#pragma unroll
        for (int k = 0; k < 4; k++) {
            int local = off + k;
            int p = lp[k];
            bool root = (p == local);
            cnt += root ? 1 : 0;
            if (root && local > mx) mx = local;
            if (p >= 0 && local >= 1 && local < mn) mn = local;
        }
    }
    s1[t] = cnt; s2[t] = mx; s3[t] = mn;
    __syncthreads();
    for (int s = 128; s > 0; s >>= 1) {
        if (t < s) {
            s1[t] += s1[t + s];
            s2[t] = max(s2[t], s2[t + s]);
            s3[t] = min(s3[t], s3[t + s]);
        }
        __syncthreads();
    }
    if (t == 0) {
        AS_RLX(&cntArr[chunk], s1[0]);
        AS_RLX(&maxArr[chunk], s2[0]);
        AS_RLX(&minArr[chunk], s3[0]);
        // acq_rel: releases the stores above, acquires others' on last finish
        oldc = __hip_atomic_fetch_add(&counters[img], 1u,
                                      __ATOMIC_ACQ_REL, __HIP_MEMORY_SCOPE_AGENT);
    }
    __syncthreads();
    if (oldc != CPI - 1) return;

    // ---- last finisher for this image: compute v, select v-th root ---------
    int c0 = (t < CPI) ? AL_ACQ(&cntArr[img * CPI + t]) : 0;
    s1[t] = c0;
    s2[t] = (t < CPI) ? AL_ACQ(&maxArr[img * CPI + t]) : -1;
    s3[t] = (t < CPI) ? AL_ACQ(&minArr[img * CPI + t]) : HW;
    if (t == 0) result = -2;
    __syncthreads();
    for (int off = 1; off < 256; off <<= 1) {     // inclusive scan of counts
        int v2 = (t >= off) ? s1[t - off] : 0;
        __syncthreads();
        s1[t] += v2;
        __syncthreads();
    }
    int num = s1[255];
    int inc = s1[t], exc = inc - c0;
    for (int s = 128; s > 0; s >>= 1) {
        if (t < s) { s2[t] = max(s2[t], s2[t + s]); s3[t] = min(s3[t], s3[t + s]); }
        __syncthreads();
    }
    int last_root = s2[0], minFg = s3[0];
    int v;
    if (last_root >= 1) v = last_root;
    else if (last_root == 0) v = (minFg < HW) ? minFg : 1;
    else v = 1;
    if (v >= 1 && v <= num) {            // block-uniform branch
        if (exc < v && v <= inc) { sel_chunk = t; sel_base = exc; }
        __syncthreads();
        int c = sel_chunk, base = sel_base;
        int bL = c * 4096;
        int f[16];
        int sum = 0;
#pragma unroll
        for (int j = 0; j < 4; j++) {
            int off = bL + t * 16 + j * 4;
            int4 l4 = *(const int4*)(Li + off);
            const int* lp = (const int*)&l4;
#pragma unroll
            for (int k = 0; k < 4; k++) {
                f[j * 4 + k] = (lp[k] == off + k) ? 1 : 0;
                sum += f[j * 4 + k];
            }
        }
        __syncthreads();                  // done reading s1 from scan 1
        s1[t] = sum;
        __syncthreads();
        for (int off = 1; off < 256; off <<= 1) {
            int v2 = (t >= off) ? s1[t - off] : 0;
            __syncthreads();
            s1[t] += v2;
            __syncthreads();
        }
        int exc2 = s1[t] - sum;
        int need = v - base;
        if (exc2 < need && need <= s1[t]) {
            int run = exc2;
#pragma unroll
            for (int k = 0; k < 16; k++) {
                run += f[k];
                if (run == need) { result = bL + t * 16 + k; break; }
            }
        }
        __syncthreads();
    } else {
        __syncthreads();
    }
    if (t == 0) rv[img] = result;
}

// ---------------- K4: correction term + fused final reduce ------------------
// correction = sum_{root==rv}(logp - log1mp); rv = -2 (empty target) is the
// common case -> blocks store 0 and leave. Grid counter elects the last
// finisher, which reduces partials (cross-kernel, plain reads) + partials2
// (intra-kernel, acquire atomic reads) in double and writes the scalar out.
__global__ __launch_bounds__(256) void k_loss(const float* __restrict__ pred,
                                              const int* __restrict__ L,
                                              const int* __restrict__ rvArr,
                                              const float* __restrict__ partials,
                                              float* __restrict__ partials2,
                                              unsigned int* __restrict__ counters,
                                              float* __restrict__ out) {
    __shared__ float sred[256];
    __shared__ double sd[256];
    __shared__ unsigned int oldc;
    int blk = blockIdx.x;                // 2048 blocks x 4096 px
    int img = blk >> 6;
    int t = threadIdx.x;
    int rvv = rvArr[img];
    float blocksum = 0.0f;
    if (rvv >= 0) {                      // block-uniform; dead for rv=-2
        const int* Li = L + ((size_t)img << LOGHW);
        int baseG = blk * 4096;
        float acc = 0.0f;
#pragma unroll
        for (int j = 0; j < 4; j++) {
            int off = baseG + (t + j * 256) * 4;
            float4 p4 = *(const float4*)(pred + off);
            int4 l4 = *(const int4*)(L + off);
            const float* pp = (const float*)&p4;
            const int* lp = (const int*)&l4;
#pragma unroll
            for (int k = 0; k < 4; k++) {
                int p = lp[k];
                if (p < 0) continue;
                int x = p, q = Li[x];
                while (q != x) { x = q; q = Li[x]; }   // chase to root
                if (x == rvv) {
                    float pr = pp[k];
                    acc += fmaxf(__logf(pr), -100.0f)
                         - fmaxf(__logf(1.0f - pr), -100.0f);
                }
            }
        }
        sred[t] = acc;
        __syncthreads();
        for (int s = 128; s > 0; s >>= 1) {
            if (t < s) sred[t] += sred[t + s];
            __syncthreads();
        }
        blocksum = sred[0];
    }
    if (t == 0) {
        AS_RLX(&partials2[blk], blocksum);
        oldc = __hip_atomic_fetch_add(&counters[NIMG], 1u,
                                      __ATOMIC_ACQ_REL, __HIP_MEMORY_SCOPE_AGENT);
    }
    __syncthreads();
    if (oldc != NTILE - 1) return;

    // ---- last finisher: final reduce of 2 x 2048 partials ------------------
    double acc = 0.0;
#pragma unroll
    for (int j = 0; j < 8; j++) {
        int idx = t + j * 256;
        acc += (double)partials[idx] + (double)AL_ACQ(&partials2[idx]);
    }
    sd[t] = acc;
    __syncthreads();
    for (int s = 128; s > 0; s >>= 1) {
        if (t < s) sd[t] += sd[t + s];
        __syncthreads();
    }
    if (t == 0) out[0] = (float)(-sd[0] / (double)NTOT);
}

extern "C" void kernel_launch(void* const* d_in, const int* in_sizes, int n_in,
                              void* d_out, int out_size, void* d_ws, size_t ws_size,
                              hipStream_t stream) {
    const float* pred = (const float*)d_in[0];
    float* out = (float*)d_out;

    char* ws = (char*)d_ws;
    int* L = (int*)ws;                                        // 33.5 MB
    int* cntArr = (int*)(ws + (size_t)NTOT * 4);              // 8 KB
    int* maxArr = cntArr + NSCHUNK;                           // 8 KB
    int* minArr = maxArr + NSCHUNK;                           // 8 KB
    float* partials = (float*)(minArr + NSCHUNK);             // 8 KB
    float* partials2 = partials + NTILE;                      // 8 KB
    int* rv = (int*)(partials2 + NTILE);                      // 128 B
    unsigned int* counters = (unsigned int*)(rv + NIMG);      // 33 slots

    k_local<<<dim3(NTILE), dim3(1024), 0, stream>>>(pred, L, partials, counters);
    k_border<<<dim3(NBORD / 256), dim3(256), 0, stream>>>(L);
    k_stats_rv<<<dim3(NSCHUNK), dim3(256), 0, stream>>>(L, cntArr, maxArr, minArr,
                                                        counters, rv);
    k_loss<<<dim3(NTILE), dim3(256), 0, stream>>>(pred, L, rv, partials, partials2,
                                                  counters, out);
}

// Round 7
// 123.556 us; speedup vs baseline: 1.8124x; 1.8124x over previous
//
#include <hip/hip_runtime.h>
#include <math.h>

// Problem constants (fixed by reference setup_inputs): pred [32,1,512,512] f32
#define IMG_W 512
#define IMG_H 512
#define HW (IMG_W * IMG_H)      // 262144 = 2^18
#define LOGHW 18
#define NIMG 32
#define NTOT (NIMG * HW)        // 8388608
#define TILE 64
#define TPI 64                  // 8x8 tiles of 64x64 per image
#define NTILE (NIMG * TPI)      // 2048
#define CPI 64                  // stat-chunks per image (4096 px each)
#define NSCHUNK (NIMG * CPI)    // 2048
#define VBORD ((8 - 1) * IMG_H)                 // 3584 vertical-border pairs/img
#define BORD_PER_IMG (VBORD + (8 - 1) * IMG_W)  // 7168
#define NBORD (NIMG * BORD_PER_IMG)             // 229376

// NOTE (R6 lesson): NO cross-kernel single-counter handshakes. 2048 acq_rel
// fetch_adds to one address serialize at ~27ns each = 56us of dead time.
// Separate tiny kernels cost ~4us launch — strictly cheaper.

// ---------------- lock-free min-index union-find ----------------------------
__device__ __forceinline__ void uf_unite(int* L, int a, int b) {
    while (true) {
        // find roots (reads may be stale -> only costs retries, never wrong)
        int p = ((volatile int*)L)[a];
        while (p != a) { a = p; p = ((volatile int*)L)[a]; }
        p = ((volatile int*)L)[b];
        while (p != b) { b = p; p = ((volatile int*)L)[b]; }
        if (a == b) return;
        if (a < b) { int t = a; a = b; b = t; }  // a > b
        int old = atomicMin(&L[a], b);
        if (old == a) return;
        a = old;
    }
}

// ---------------- K1: CCL (ballot row-runs + vertical unites) + base BCE ----
// One block (512 thr, 8 waves) per 64x64 tile; tile row width == wave width.
// Row runs labeled in O(1) via ballot (run start = min index of run). Only
// vertical run-pair contacts go through the LDS union-find (~750/tile).
// Local raster order == global raster order within a tile, so min-index roots
// are exact. Base BCE term sum(fmax(log(1-p),-100)) fused with native __logf
// (~4 VALU ops/px; R4's regression was ocml log1pf's ~30) — pred is then read
// exactly once across the whole pipeline in the common rv=-2 case.
__global__ __launch_bounds__(512) void k_local(const float* __restrict__ pred,
                                               int* __restrict__ L,
                                               float* __restrict__ partials) {
    __shared__ int lab[TILE * TILE];   // 16 KB
    __shared__ float sred[512];        // 2 KB
    int tile = blockIdx.x;
    int img = tile >> 6;
    int t = tile & (TPI - 1);
    int ty = t >> 3, tx = t & 7;
    int baseLocal = (ty * TILE) * IMG_W + tx * TILE;  // image-local origin
    const float* pi = pred + ((size_t)img << LOGHW);
    int* Li = L + ((size_t)img << LOGHW);
    int tid = threadIdx.x;
    int lane = tid & 63, wave = tid >> 6;             // wave 0..7

    float acc = 0.0f;
    // ---- pass 1: row-run labels via ballot (wave w handles rows r%8==w) ----
#pragma unroll
    for (int j = 0; j < 8; j++) {
        int row = wave + j * 8;
        float p = pi[baseLocal + row * IMG_W + lane];
        acc += fmaxf(__logf(1.0f - p), -100.0f);   // 1-p exact for p>=0.5
        bool fg = (p >= 0.5f);
        unsigned long long bal = __ballot(fg);
        unsigned long long starts = bal & ~(bal << 1);
        unsigned long long maskle =
            (lane == 63) ? ~0ULL : ((1ULL << (lane + 1)) - 1ULL);
        int lb = -1;
        if (fg) {
            unsigned long long pre = starts & maskle;   // nonzero when fg
            lb = row * TILE + (63 - __builtin_clzll(pre));
        }
        lab[row * TILE + lane] = lb;
    }
    __syncthreads();
    // ---- pass 2: vertical unites, one per contact-run ----------------------
#pragma unroll
    for (int j = 0; j < 8; j++) {
        int row = wave + j * 8;
        if (row == 0) continue;                   // wave-uniform
        int i = row * TILE + lane;
        bool c = (lab[i] >= 0) && (lab[i - TILE] >= 0);
        unsigned long long cb = __ballot(c);
        unsigned long long cs = cb & ~(cb << 1);  // first lane of each contact
        if ((cs >> lane) & 1ULL) uf_unite(lab, i, i - TILE);
    }
    __syncthreads();
    // ---- pass 3: flatten (path halving) + write image-local roots (int4) ---
#pragma unroll
    for (int j = 0; j < 2; j++) {
        int i4 = (tid + j * 512) * 4;
        int ly = i4 >> 6, lx = i4 & 63;
        int4 o;
        int* op = (int*)&o;
#pragma unroll
        for (int k = 0; k < 4; k++) {
            int x = i4 + k;
            int p = lab[x];
            if (p < 0) op[k] = -1;
            else {
                while (p != x) {
                    int g = lab[p];     // grandparent (or parent if p is root)
                    lab[x] = g;         // path halving: benign race
                    x = g;
                    p = lab[x];
                }
                op[k] = baseLocal + (x >> 6) * IMG_W + (x & 63);
            }
        }
        *(int4*)(Li + baseLocal + ly * IMG_W + lx) = o;
    }
    // ---- base BCE block reduce ---------------------------------------------
    sred[tid] = acc;
    __syncthreads();
    for (int s = 256; s > 0; s >>= 1) {
        if (tid < s) sred[tid] += sred[tid + s];
        __syncthreads();
    }
    if (tid == 0) partials[blockIdx.x] = sred[0];
}

// ---------------- K2: cross-tile border unites, ballot-compressed -----------
// Consecutive contact pairs along an edge are redundant (edge-parallel
// neighbors already united intra-tile): unite only at contact-run starts.
// Waves never straddle edges: 512, VBORD, BORD_PER_IMG all multiples of 64.
__global__ void k_border(int* __restrict__ L) {
    int gid = blockIdx.x * blockDim.x + threadIdx.x;
    int img = gid / BORD_PER_IMG;                // wave-uniform
    int r = gid - img * BORD_PER_IMG;
    int* Li = L + ((size_t)img << LOGHW);
    int a, b;
    if (r < VBORD) {                             // wave-uniform branch
        int k = r >> 9, y = r & 511;
        int x = k * TILE + (TILE - 1);
        a = y * IMG_W + x; b = a + 1;
    } else {
        int r2 = r - VBORD;
        int k = r2 >> 9, x = r2 & 511;
        int y = k * TILE + (TILE - 1);
        a = y * IMG_W + x; b = a + IMG_W;
    }
    bool c = (Li[a] >= 0) && (Li[b] >= 0);
    unsigned long long cb = __ballot(c);
    unsigned long long cs = cb & ~(cb << 1);     // contact-run starts
    if ((cs >> (threadIdx.x & 63)) & 1ULL) uf_unite(Li, a, b);
}

// ---------------- K3: per-chunk stats (4096 px): roots, maxRoot, minFg ------
// Root flags (L[i]==i) are invariant under path compression: no chase needed.
__global__ __launch_bounds__(256) void k_stats(const int* __restrict__ L,
                                               int* __restrict__ cntArr,
                                               int* __restrict__ maxArr,
                                               int* __restrict__ minArr) {
    __shared__ int s1[256], s2[256], s3[256];
    int chunk = blockIdx.x;
    int img = chunk >> 6;
    int baseL = (chunk & 63) * 4096;             // image-local
    const int* Li = L + ((size_t)img << LOGHW);
    int t = threadIdx.x;
    int cnt = 0, mx = -1, mn = HW;
#pragma unroll
    for (int j = 0; j < 4; j++) {
        int off = baseL + (t + j * 256) * 4;
        int4 l4 = *(const int4*)(Li + off);
        const int* lp = (const int*)&l4;
#pragma unroll
        for (int k = 0; k < 4; k++) {
            int local = off + k;
            int p = lp[k];
            bool root = (p == local);
            cnt += root ? 1 : 0;
            if (root && local > mx) mx = local;
            if (p >= 0 && local >= 1 && local < mn) mn = local;
        }
    }
    s1[t] = cnt; s2[t] = mx; s3[t] = mn;
    __syncthreads();
    for (int s = 128; s > 0; s >>= 1) {
        if (t < s) {
            s1[t] += s1[t + s];
            s2[t] = max(s2[t], s2[t + s]);
            s3[t] = min(s3[t], s3[t + s]);
        }
        __syncthreads();
    }
    if (t == 0) { cntArr[chunk] = s1[0]; maxArr[chunk] = s2[0]; minArr[chunk] = s3[0]; }
}

// ---------------- K4: per-image v + select v-th root -> rv[img] -------------
// v = argmax(lf[1:]) + 1 equals: index of LAST root (if >=1); else (single
// component rooted at 0) the first fg index >=1, or 1 if none; else 1.
// rv = v-th root in raster order if 1<=v<=num, else -2 (target empty).
__global__ __launch_bounds__(256) void k_rv(const int* __restrict__ cntArr,
                                            const int* __restrict__ maxArr,
                                            const int* __restrict__ minArr,
                                            const int* __restrict__ L,
                                            int* __restrict__ rv) {
    __shared__ int sc[256], sm[256], sn[256];
    __shared__ int sel_chunk, sel_base, result;
    int img = blockIdx.x, t = threadIdx.x;
    int cnt = (t < CPI) ? cntArr[img * CPI + t] : 0;
    sc[t] = cnt;
    sm[t] = (t < CPI) ? maxArr[img * CPI + t] : -1;
    sn[t] = (t < CPI) ? minArr[img * CPI + t] : HW;
    if (t == 0) result = -2;
    __syncthreads();
    // inclusive scan of counts
    for (int off = 1; off < 256; off <<= 1) {
        int v2 = (t >= off) ? sc[t - off] : 0;
        __syncthreads();
        sc[t] += v2;
        __syncthreads();
    }
    int num = sc[255];
    int inc = sc[t], exc = inc - cnt;
    // max/min reduce (syncs also fence the num/inc/exc reads above)
    for (int s = 128; s > 0; s >>= 1) {
        if (t < s) { sm[t] = max(sm[t], sm[t + s]); sn[t] = min(sn[t], sn[t + s]); }
        __syncthreads();
    }
    int last_root = sm[0], minFg = sn[0];
    int v;
    if (last_root >= 1) v = last_root;
    else if (last_root == 0) v = (minFg < HW) ? minFg : 1;
    else v = 1;
    if (v >= 1 && v <= num) {            // block-uniform branch
        if (exc < v && v <= inc) { sel_chunk = t; sel_base = exc; }
        __syncthreads();
        int c = sel_chunk, base = sel_base;
        const int* Li = L + ((size_t)img << LOGHW);
        int baseL = c * 4096;
        int f[16];
        int sum = 0;
#pragma unroll
        for (int j = 0; j < 4; j++) {
            int off = baseL + t * 16 + j * 4;
            int4 l4 = *(const int4*)(Li + off);
            const int* lp = (const int*)&l4;
#pragma unroll
            for (int k = 0; k < 4; k++) {
                f[j * 4 + k] = (lp[k] == off + k) ? 1 : 0;
                sum += f[j * 4 + k];
            }
        }
        __syncthreads();                  // done reading sc from scan 1
        sc[t] = sum;
        __syncthreads();
        for (int off = 1; off < 256; off <<= 1) {
            int v2 = (t >= off) ? sc[t - off] : 0;
            __syncthreads();
            sc[t] += v2;
            __syncthreads();
        }
        int exc2 = sc[t] - sum;
        int need = v - base;
        if (exc2 < need && need <= sc[t]) {
            int run = exc2;
#pragma unroll
            for (int k = 0; k < 16; k++) {
                run += f[k];
                if (run == need) { result = baseL + t * 16 + k; break; }
            }
        }
        __syncthreads();
    } else {
        __syncthreads();
    }
    if (t == 0) rv[img] = result;
}

// ---------------- K5: correction term sum_{root==rv}(logp - log1mp) ---------
// rv = -2 (target empty) is the common case for random input: write 0, leave.
// Base BCE already accumulated in k_local.
__global__ __launch_bounds__(256) void k_loss(const float* __restrict__ pred,
                                              const int* __restrict__ L,
                                              const int* __restrict__ rvArr,
                                              float* __restrict__ partials2) {
    __shared__ float sred[256];
    int blk = blockIdx.x;                // 2048 blocks x 4096 px
    int img = blk >> 6;
    int t = threadIdx.x;
    int rvv = rvArr[img];
    if (rvv < 0) {                       // block-uniform; the common case
        if (t == 0) partials2[blk] = 0.0f;
        return;
    }
    const int* Li = L + ((size_t)img << LOGHW);
    int baseG = blk * 4096;
    float acc = 0.0f;
#pragma unroll
    for (int j = 0; j < 4; j++) {
        int off = baseG + (t + j * 256) * 4;
        float4 p4 = *(const float4*)(pred + off);
        int4 l4 = *(const int4*)(L + off);
        const float* pp = (const float*)&p4;
        const int* lp = (const int*)&l4;
#pragma unroll
        for (int k = 0; k < 4; k++) {
            int p = lp[k];
            if (p < 0) continue;
            int x = p, q = Li[x];
            while (q != x) { x = q; q = Li[x]; }   // chase to root
            if (x == rvv) {
                float pr = pp[k];
                acc += fmaxf(__logf(pr), -100.0f)
                     - fmaxf(__logf(1.0f - pr), -100.0f);
            }
        }
    }
    sred[t] = acc;
    __syncthreads();
    for (int s = 128; s > 0; s >>= 1) {
        if (t < s) sred[t] += sred[t + s];
        __syncthreads();
    }
    if (t == 0) partials2[blk] = sred[0];
}

// ---------------- K6: final reduce ------------------------------------------
__global__ __launch_bounds__(256) void k_final(const float* __restrict__ partials,
                                               const float* __restrict__ partials2,
                                               float* __restrict__ out) {
    __shared__ double s[256];
    int t = threadIdx.x;
    double acc = 0.0;
#pragma unroll
    for (int j = 0; j < 8; j++) {
        int idx = t + j * 256;
        acc += (double)partials[idx] + (double)partials2[idx];
    }
    s[t] = acc;
    __syncthreads();
    for (int st = 128; st > 0; st >>= 1) {
        if (t < st) s[t] += s[t + st];
        __syncthreads();
    }
    if (t == 0) out[0] = (float)(-s[0] / (double)NTOT);
}

extern "C" void kernel_launch(void* const* d_in, const int* in_sizes, int n_in,
                              void* d_out, int out_size, void* d_ws, size_t ws_size,
                              hipStream_t stream) {
    const float* pred = (const float*)d_in[0];
    float* out = (float*)d_out;

    char* ws = (char*)d_ws;
    int* L = (int*)ws;                                        // 33.5 MB
    int* cntArr = (int*)(ws + (size_t)NTOT * 4);              // 8 KB
    int* maxArr = cntArr + NSCHUNK;                           // 8 KB
    int* minArr = maxArr + NSCHUNK;                           // 8 KB
    float* partials = (float*)(minArr + NSCHUNK);             // 8 KB
    float* partials2 = partials + NTILE;                      // 8 KB
    int* rv = (int*)(partials2 + NSCHUNK);                    // 128 B

    k_local<<<dim3(NTILE), dim3(512), 0, stream>>>(pred, L, partials);
    k_border<<<dim3(NBORD / 256), dim3(256), 0, stream>>>(L);
    k_stats<<<dim3(NSCHUNK), dim3(256), 0, stream>>>(L, cntArr, maxArr, minArr);
    k_rv<<<dim3(NIMG), dim3(256), 0, stream>>>(cntArr, maxArr, minArr, L, rv);
    k_loss<<<dim3(NSCHUNK), dim3(256), 0, stream>>>(pred, L, rv, partials2);
    k_final<<<1, dim3(256), 0, stream>>>(partials, partials2, out);
}

// Round 8
// 121.068 us; speedup vs baseline: 1.8496x; 1.0206x over previous
//
#include <hip/hip_runtime.h>
#include <math.h>

// Problem constants (fixed by reference setup_inputs): pred [32,1,512,512] f32
#define IMG_W 512
#define IMG_H 512
#define HW (IMG_W * IMG_H)      // 262144 = 2^18
#define LOGHW 18
#define NIMG 32
#define NTOT (NIMG * HW)        // 8388608
#define TILE 64
#define TPI 64                  // 8x8 tiles of 64x64 per image
#define NTILE (NIMG * TPI)      // 2048
#define CPI 64                  // stat-chunks per image (4096 px each)
#define NSCHUNK (NIMG * CPI)    // 2048
#define EDGE_N (NTILE * 64)     // 131072 entries per edge direction
#define NPAIR (NIMG * 112)      // 56 vertical + 56 horizontal tile-pairs/img
// NOTE (R6 lesson): NO wide cross-kernel counter handshakes. 2048 acq_rel
// fetch_adds to one address serialize ~27ns each = 56us dead. 32-way is fine.

// ---------------- lock-free min-index union-find ----------------------------
__device__ __forceinline__ void uf_unite(int* L, int a, int b) {
    while (true) {
        // find roots (reads may be stale -> only costs retries, never wrong)
        int p = ((volatile int*)L)[a];
        while (p != a) { a = p; p = ((volatile int*)L)[a]; }
        p = ((volatile int*)L)[b];
        while (p != b) { b = p; p = ((volatile int*)L)[b]; }
        if (a == b) return;
        if (a < b) { int t = a; a = b; b = t; }  // a > b
        int old = atomicMin(&L[a], b);
        if (old == a) return;
        a = old;
    }
}

// ---------------- K1: CCL + base BCE + edge export --------------------------
// One block (512 thr, 8 waves) per 64x64 tile; row width == wave width.
// Pass 1: row-run labels via ballot (run start = min index of run) + fused
//   base BCE sum(fmax(log(1-p),-100)) with native __logf.
// Pass 2: vertical unites only at contact-run starts (~750/tile). Unites
//   touch only ROOT entries, and roots are always run-starts; non-start
//   entries keep their run-start pointer forever.
// Pass 3a: only run-starts chase to root (full compress) — ~1000 instead of
//   4096 scattered chases (R7: 2.07M LDS conflict cycles came from here).
// Pass 3b: every px root = lab[lab[px]] (2 LDS reads, broadcast-friendly);
//   write global L; export the 4 tile-edge label vectors coalesced for
//   k_border (kills its 2KB-strided detection reads).
__global__ __launch_bounds__(512) void k_local(const float* __restrict__ pred,
                                               int* __restrict__ L,
                                               float* __restrict__ partials,
                                               int* __restrict__ edges,
                                               unsigned int* __restrict__ counter) {
    __shared__ int lab[TILE * TILE];   // 16 KB
    __shared__ float sred[512];        // 2 KB
    int tile = blockIdx.x;
    int img = tile >> 6;
    int t = tile & (TPI - 1);
    int ty = t >> 3, tx = t & 7;
    int baseLocal = (ty * TILE) * IMG_W + tx * TILE;  // image-local origin
    const float* pi = pred + ((size_t)img << LOGHW);
    int* Li = L + ((size_t)img << LOGHW);
    int tid = threadIdx.x;
    int lane = tid & 63, wave = tid >> 6;             // wave 0..7

    float acc = 0.0f;
    // ---- pass 1: row-run labels via ballot ---------------------------------
#pragma unroll
    for (int j = 0; j < 8; j++) {
        int row = wave + j * 8;
        float p = pi[baseLocal + row * IMG_W + lane];
        acc += fmaxf(__logf(1.0f - p), -100.0f);   // 1-p exact for p>=0.5
        bool fg = (p >= 0.5f);
        unsigned long long bal = __ballot(fg);
        unsigned long long starts = bal & ~(bal << 1);
        unsigned long long maskle =
            (lane == 63) ? ~0ULL : ((1ULL << (lane + 1)) - 1ULL);
        int lb = -1;
        if (fg) {
            unsigned long long pre = starts & maskle;   // nonzero when fg
            lb = row * TILE + (63 - __builtin_clzll(pre));
        }
        lab[row * TILE + lane] = lb;
    }
    __syncthreads();
    // ---- pass 2: vertical unites, one per contact-run ----------------------
#pragma unroll
    for (int j = 0; j < 8; j++) {
        int row = wave + j * 8;
        if (row == 0) continue;                   // wave-uniform
        int i = row * TILE + lane;
        bool c = (lab[i] >= 0) && (lab[i - TILE] >= 0);
        unsigned long long cb = __ballot(c);
        unsigned long long cs = cb & ~(cb << 1);  // first lane of each contact
        if ((cs >> lane) & 1ULL) uf_unite(lab, i, i - TILE);
    }
    __syncthreads();
    // ---- pass 3a: run-starts chase to root (path halving + full compress) --
#pragma unroll
    for (int j = 0; j < 8; j++) {
        int row = wave + j * 8;
        int i = row * TILE + lane;
        bool fg = (lab[i] >= 0);
        unsigned long long bal = __ballot(fg);
        unsigned long long st = bal & ~(bal << 1);
        if ((st >> lane) & 1ULL) {
            int x = i, p = lab[x];
            while (p != x) {
                int g = lab[p];
                lab[x] = g;          // halving: benign race, ancestors only
                x = g;
                p = lab[x];
            }
            lab[i] = x;              // full compress for the start entry
        }
    }
    __syncthreads();
    // ---- pass 3b: gather roots (2 LDS reads/px) + global write (int4) ------
#pragma unroll
    for (int j = 0; j < 2; j++) {
        int i4 = (tid + j * 512) * 4;
        int ly = i4 >> 6, lx = i4 & 63;
        int4 o;
        int* op = (int*)&o;
#pragma unroll
        for (int k = 0; k < 4; k++) {
            int s = lab[i4 + k];                 // runstart (or root if start)
            if (s < 0) op[k] = -1;
            else {
                int r = lab[s];                  // root (starts compressed)
                op[k] = baseLocal + (r >> 6) * IMG_W + (r & 63);
            }
        }
        *(int4*)(Li + baseLocal + ly * IMG_W + lx) = o;
    }
    // ---- edge export: 4 x 64 labels, coalesced -----------------------------
    if (tid < 256) {
        int e = tid >> 6;                        // 0=T,1=B,2=L,3=R
        int q = tid & 63;
        int px = (e == 0) ? q
               : (e == 1) ? (63 * TILE + q)
               : (e == 2) ? (q * TILE)
               :            (q * TILE + 63);
        int s = lab[px];
        int val = -1;
        if (s >= 0) {
            int r = lab[s];
            val = baseLocal + (r >> 6) * IMG_W + (r & 63);
        }
        edges[e * EDGE_N + tile * 64 + q] = val;
    }
    // ---- base BCE block reduce ---------------------------------------------
    sred[tid] = acc;
    __syncthreads();
    for (int s = 256; s > 0; s >>= 1) {
        if (tid < s) sred[tid] += sred[tid + s];
        __syncthreads();
    }
    if (tid == 0) partials[blockIdx.x] = sred[0];
    if (blockIdx.x == 0 && tid == 0) *counter = 0u;   // ws is 0xAA-poisoned
}

// ---------------- K2: cross-tile border unites from compact edges -----------
// One wave per tile-pair edge (64 lanes = 64 contact positions). Detection
// reads are fully coalesced from the 2MB edge buffer; unites start directly
// from the stored tile-roots. Consecutive contacts along an edge are
// redundant (edge-parallel neighbors already united intra-tile): unite only
// at contact-run starts.
__global__ __launch_bounds__(256) void k_border(const int* __restrict__ edges,
                                                int* __restrict__ L) {
    int gid = blockIdx.x * blockDim.x + threadIdx.x;
    int pair = gid >> 6;                 // wave-uniform
    int lane = gid & 63;
    int a, b, img;
    if (pair < NIMG * 56) {              // vertical: (ty,tx)-(ty,tx+1)
        img = pair / 56;
        int w = pair - img * 56;
        int ty = w / 7, tx = w - ty * 7;
        int tl = img * TPI + ty * 8 + tx;
        a = edges[3 * EDGE_N + tl * 64 + lane];        // right edge of left
        b = edges[2 * EDGE_N + (tl + 1) * 64 + lane];  // left edge of right
    } else {                             // horizontal: (ty,tx)-(ty+1,tx)
        int p2 = pair - NIMG * 56;
        img = p2 / 56;
        int w = p2 - img * 56;
        int ty = w >> 3, tx = w & 7;
        int tu = img * TPI + ty * 8 + tx;
        a = edges[1 * EDGE_N + tu * 64 + lane];        // bottom edge of upper
        b = edges[0 * EDGE_N + (tu + 8) * 64 + lane];  // top edge of lower
    }
    bool c = (a >= 0) && (b >= 0);
    unsigned long long cb = __ballot(c);
    unsigned long long cs = cb & ~(cb << 1);           // contact-run starts
    if ((cs >> lane) & 1ULL)
        uf_unite(L + ((size_t)img << LOGHW), a, b);
}

// ---------------- K3: per-chunk stats (4096 px): roots, maxRoot, minFg ------
// Root flags (L[i]==i) are invariant under path compression: no chase needed.
__global__ __launch_bounds__(256) void k_stats(const int* __restrict__ L,
                                               int* __restrict__ cntArr,
                                               int* __restrict__ maxArr,
                                               int* __restrict__ minArr) {
    __shared__ int s1[256], s2[256], s3[256];
    int chunk = blockIdx.x;
    int img = chunk >> 6;
    int baseL = (chunk & 63) * 4096;             // image-local
    const int* Li = L + ((size_t)img << LOGHW);
    int t = threadIdx.x;
    int cnt = 0, mx = -1, mn = HW;
#pragma unroll
    for (int j = 0; j < 4; j++) {
        int off = baseL + (t + j * 256) * 4;
        int4 l4 = *(const int4*)(Li + off);
        const int* lp = (const int*)&l4;
#pragma unroll
        for (int k = 0; k < 4; k++) {
            int local = off + k;
            int p = lp[k];
            bool root = (p == local);
            cnt += root ? 1 : 0;
            if (root && local > mx) mx = local;
            if (p >= 0 && local >= 1 && local < mn) mn = local;
        }
    }
    s1[t] = cnt; s2[t] = mx; s3[t] = mn;
    __syncthreads();
    for (int s = 128; s > 0; s >>= 1) {
        if (t < s) {
            s1[t] += s1[t + s];
            s2[t] = max(s2[t], s2[t + s]);
            s3[t] = min(s3[t], s3[t + s]);
        }
        __syncthreads();
    }
    if (t == 0) { cntArr[chunk] = s1[0]; maxArr[chunk] = s2[0]; minArr[chunk] = s3[0]; }
}

// ---------------- K4: fused rv + correction + final reduce ------------------
// One block per image. v = argmax(lf[1:]) + 1 equals: index of LAST root
// (if >=1); else (single component rooted at 0) first fg index >=1, or 1 if
// none; else 1. rv = v-th root in raster order if 1<=v<=num, else -2.
// If rv >= 0 (rare), this block scans its image for the correction term
// sum_{root==rv}(logp - log1mp). Last of the 32 blocks (32-way counter, not
// R6's 2048-way) reduces k_local's 2048 base partials + 32 corrections.
__global__ __launch_bounds__(256) void k_tail(const int* __restrict__ cntArr,
                                              const int* __restrict__ maxArr,
                                              const int* __restrict__ minArr,
                                              const int* __restrict__ L,
                                              const float* __restrict__ pred,
                                              const float* __restrict__ partials,
                                              float* __restrict__ corr,
                                              unsigned int* __restrict__ counter,
                                              float* __restrict__ out) {
    __shared__ int sc[256], sm[256], sn[256];
    __shared__ int sel_chunk, sel_base, result;
    __shared__ float sf[256];
    __shared__ double sd[256];
    __shared__ unsigned int oldc;
    int img = blockIdx.x, t = threadIdx.x;
    const int* Li = L + ((size_t)img << LOGHW);
    int cnt = (t < CPI) ? cntArr[img * CPI + t] : 0;
    sc[t] = cnt;
    sm[t] = (t < CPI) ? maxArr[img * CPI + t] : -1;
    sn[t] = (t < CPI) ? minArr[img * CPI + t] : HW;
    if (t == 0) result = -2;
    __syncthreads();
    for (int off = 1; off < 256; off <<= 1) {    // inclusive scan of counts
        int v2 = (t >= off) ? sc[t - off] : 0;
        __syncthreads();
        sc[t] += v2;
        __syncthreads();
    }
    int num = sc[255];
    int inc = sc[t], exc = inc - cnt;
    for (int s = 128; s > 0; s >>= 1) {
        if (t < s) { sm[t] = max(sm[t], sm[t + s]); sn[t] = min(sn[t], sn[t + s]); }
        __syncthreads();
    }
    int last_root = sm[0], minFg = sn[0];
    int v;
    if (last_root >= 1) v = last_root;
    else if (last_root == 0) v = (minFg < HW) ? minFg : 1;
    else v = 1;
    if (v >= 1 && v <= num) {            // block-uniform branch
        if (exc < v && v <= inc) { sel_chunk = t; sel_base = exc; }
        __syncthreads();
        int c = sel_chunk, base = sel_base;
        int baseL = c * 4096;
        int f[16];
        int sum = 0;
#pragma unroll
        for (int j = 0; j < 4; j++) {
            int off = baseL + t * 16 + j * 4;
            int4 l4 = *(const int4*)(Li + off);
            const int* lp = (const int*)&l4;
#pragma unroll
            for (int k = 0; k < 4; k++) {
                f[j * 4 + k] = (lp[k] == off + k) ? 1 : 0;
                sum += f[j * 4 + k];
            }
        }
        __syncthreads();
        sc[t] = sum;
        __syncthreads();
        for (int off = 1; off < 256; off <<= 1) {
            int v2 = (t >= off) ? sc[t - off] : 0;
            __syncthreads();
            sc[t] += v2;
            __syncthreads();
        }
        int exc2 = sc[t] - sum;
        int need = v - base;
        if (exc2 < need && need <= sc[t]) {
            int run = exc2;
#pragma unroll
            for (int k = 0; k < 16; k++) {
                run += f[k];
                if (run == need) { result = baseL + t * 16 + k; break; }
            }
        }
        __syncthreads();
    } else {
        __syncthreads();
    }
    int rvv = result;
    float blocksum = 0.0f;
    if (rvv >= 0) {                      // rare path: scan whole image
        const float* pi = pred + ((size_t)img << LOGHW);
        float acc = 0.0f;
        for (int it = 0; it < HW / 1024; it++) {
            int off = it * 1024 + t * 4;
            float4 p4 = *(const float4*)(pi + off);
            int4 l4 = *(const int4*)(Li + off);
            const float* pp = (const float*)&p4;
            const int* lp = (const int*)&l4;
#pragma unroll
            for (int k = 0; k < 4; k++) {
                int p = lp[k];
                if (p < 0) continue;
                int x = p, q = Li[x];
                while (q != x) { x = q; q = Li[x]; }
                if (x == rvv) {
                    float pr = pp[k];
                    acc += fmaxf(__logf(pr), -100.0f)
                         - fmaxf(__logf(1.0f - pr), -100.0f);
                }
            }
        }
        sf[t] = acc;
        __syncthreads();
        for (int s = 128; s > 0; s >>= 1) {
            if (t < s) sf[t] += sf[t + s];
            __syncthreads();
        }
        blocksum = sf[0];
    }
    if (t == 0) {
        __hip_atomic_store(&corr[img], blocksum, __ATOMIC_RELAXED,
                           __HIP_MEMORY_SCOPE_AGENT);
        oldc = __hip_atomic_fetch_add(counter, 1u, __ATOMIC_ACQ_REL,
                                      __HIP_MEMORY_SCOPE_AGENT);
    }
    __syncthreads();
    if (oldc != NIMG - 1) return;
    // ---- last of 32 blocks: final reduce -----------------------------------
    double acc = 0.0;
#pragma unroll
    for (int j = 0; j < 8; j++) acc += (double)partials[t + j * 256];
    if (t < NIMG)
        acc += (double)__hip_atomic_load(&corr[t], __ATOMIC_ACQUIRE,
                                         __HIP_MEMORY_SCOPE_AGENT);
    sd[t] = acc;
    __syncthreads();
    for (int s = 128; s > 0; s >>= 1) {
        if (t < s) sd[t] += sd[t + s];
        __syncthreads();
    }
    if (t == 0) out[0] = (float)(-sd[0] / (double)NTOT);
}

extern "C" void kernel_launch(void* const* d_in, const int* in_sizes, int n_in,
                              void* d_out, int out_size, void* d_ws, size_t ws_size,
                              hipStream_t stream) {
    const float* pred = (const float*)d_in[0];
    float* out = (float*)d_out;

    char* ws = (char*)d_ws;
    int* L = (int*)ws;                                        // 33.5 MB
    int* edges = (int*)(ws + (size_t)NTOT * 4);               // 2 MB (4 dirs)
    int* cntArr = edges + 4 * EDGE_N;                         // 8 KB
    int* maxArr = cntArr + NSCHUNK;                           // 8 KB
    int* minArr = maxArr + NSCHUNK;                           // 8 KB
    float* partials = (float*)(minArr + NSCHUNK);             // 8 KB
    float* corr = partials + NTILE;                           // 128 B
    unsigned int* counter = (unsigned int*)(corr + NIMG);     // 4 B

    k_local<<<dim3(NTILE), dim3(512), 0, stream>>>(pred, L, partials, edges, counter);
    k_border<<<dim3(NPAIR * 64 / 256), dim3(256), 0, stream>>>(edges, L);
    k_stats<<<dim3(NSCHUNK), dim3(256), 0, stream>>>(L, cntArr, maxArr, minArr);
    k_tail<<<dim3(NIMG), dim3(256), 0, stream>>>(cntArr, maxArr, minArr, L, pred,
                                                 partials, corr, counter, out);
}